// Round 2
// baseline (438.201 us; speedup 1.0000x reference)
//
#include <hip/hip_runtime.h>
#include <hip/hip_bf16.h>

// Encoder layer. fp32 in/out, bf16 MFMA compute, fp32 accum.
// B=16 S=512 H=768 A=12 DH=64 F=3072.
// Round 12: gemm_v3 replaces gemm256 for QKV+FFN1.
//   BM=256 BN=128 BK=64, 8 waves (4Mx2N, wave 64x64, acc 2x2 f32x16),
//   THREE LDS buffers (3 x 48 KiB = 144 KiB), prefetch distance 2 K-tiles.
//   Per K-tile: issue 6 glds (tile kt+2) -> ds_read frags + 16 MFMA
//   (compiler-scheduled, setprio(1) around compute) -> s_waitcnt vmcnt(6)
//   (only tile kt+1's loads, issued one FULL tile ago; kt+2's stay in
//   flight) -> one raw s_barrier. No vmcnt(0) drain in steady state.
//   Round-11 failure: 2-buffer depth-1 prefetch forced vmcnt(0) per tile
//   with only ~2 phases of issue distance -> full-latency stall per tile.
// Fragment/swizzle math identical to proven gemm128: phys chunk =
// (kk*2+khalf) ^ (row&7); D swapped: lane=m, reg g*4+r -> n=8g+4*khalf+r.
// O-proj / FFN2 (N=768) stay on gemm128 (2-3 blocks/CU hides its drains).

using bf16_t = __hip_bfloat16;
typedef __bf16 bf16x8 __attribute__((ext_vector_type(8)));
typedef float f32x4 __attribute__((ext_vector_type(4)));
typedef float f32x16 __attribute__((ext_vector_type(16)));

__device__ __forceinline__ float b2f(bf16_t v) { return __bfloat162float(v); }
__device__ __forceinline__ bf16_t f2b(float v) { return __float2bfloat16(v); }
__device__ __forceinline__ ushort f2bu(float v) { bf16_t b = f2b(v); return *(ushort*)&b; }

// async global->LDS 16B copy (dest = wave base + lane*16 by construction)
__device__ __forceinline__ void glds16(const ushort* g, ushort* l) {
    __builtin_amdgcn_global_load_lds(
        (const __attribute__((address_space(1))) unsigned int*)g,
        (__attribute__((address_space(3))) unsigned int*)l, 16, 0, 0);
}

// tanh-form GELU (overflow-safe), |err vs exact| ~1e-3 << 0.102 threshold
__device__ __forceinline__ float gelu_f(float x) {
    float x2 = x * x;
    float y2 = 1.5957691216057308f * x * fmaf(0.044715f, x2, 1.0f);
    float e = __expf(y2);
    float t = 1.f - 2.f / (e + 1.f);
    return 0.5f * x * (1.f + t);
}

// ---------------------------------------------------------------------------
// Prep mega-kernel: 6 weight transposes + bias concat + X cast. One launch.
// ---------------------------------------------------------------------------
__device__ __forceinline__ void tr_tile(const float* __restrict__ in,
                                        bf16_t* __restrict__ out,
                                        int R, int C, int tx, int ty,
                                        float (*t)[65], int tid)
{
    int r0 = ty * 64, c0 = tx * 64;
    int tr = tid >> 6, tc = tid & 63;
#pragma unroll 4
    for (int i = 0; i < 16; ++i) {
        int r = i * 4 + tr;
        t[r][tc] = in[(size_t)(r0 + r) * C + c0 + tc];
    }
    __syncthreads();
#pragma unroll 4
    for (int i = 0; i < 16; ++i) {
        int r = i * 4 + tr;
        out[(size_t)(c0 + r) * R + r0 + tc] = f2b(t[tc][r]);
    }
}

__global__ __launch_bounds__(256) void prep_kernel(
    const float* __restrict__ WQ, const float* __restrict__ WK,
    const float* __restrict__ WV, const float* __restrict__ WO,
    const float* __restrict__ W1, const float* __restrict__ W2,
    const float* __restrict__ bQ, const float* __restrict__ bK,
    const float* __restrict__ bV, const float* __restrict__ X,
    bf16_t* __restrict__ Wqkv, bf16_t* __restrict__ WOt,
    bf16_t* __restrict__ W1t, bf16_t* __restrict__ W2t,
    float* __restrict__ bcat, bf16_t* __restrict__ Xb)
{
    __shared__ float t[64][65];
    const int blk = blockIdx.x, tid = threadIdx.x;
    if (blk < 576) {
        int m = blk / 144, tt = blk % 144;
        const float* in = (m == 0) ? WQ : (m == 1) ? WK : (m == 2) ? WV : WO;
        bf16_t* out = (m == 0) ? Wqkv : (m == 1) ? Wqkv + 589824
                    : (m == 2) ? Wqkv + 1179648 : WOt;
        tr_tile(in, out, 768, 768, tt % 12, tt / 12, t, tid);
    } else if (blk < 1152) {
        int tt = blk - 576;
        tr_tile(W1, W1t, 768, 3072, tt % 48, tt / 48, t, tid);
    } else if (blk < 1728) {
        int tt = blk - 1152;
        tr_tile(W2, W2t, 3072, 768, tt % 12, tt / 12, t, tid);
    } else if (blk == 1728) {
        for (int i = tid; i < 2304; i += 256)
            bcat[i] = (i < 768) ? bQ[i] : (i < 1536) ? bK[i - 768] : bV[i - 1536];
    } else {
        size_t i = ((size_t)(blk - 1729) * 256 + tid) * 8;
        float4 a = *(const float4*)(X + i);
        float4 b = *(const float4*)(X + i + 4);
#pragma unroll
        for (int j = 0; j < 4; ++j) {
            Xb[i + j]     = f2b(((const float*)&a)[j]);
            Xb[i + 4 + j] = f2b(((const float*)&b)[j]);
        }
    }
}

// ---------------------------------------------------------------------------
// gemm_v3: NT GEMM, 256x128 tile, BK=64, 512 thr = 8 waves (4Mx2N).
// Triple-buffered LDS (144 KiB dynamic), prefetch distance 2, counted vmcnt(6)
// + single raw s_barrier per K-tile. See header comment.
// EPI: 1 bias+GELU->bf16 | 6 bias, segmented QKV (see gemm128 notes).
// ---------------------------------------------------------------------------
template <int EPI>
__global__ __launch_bounds__(512, 1) void gemm_v3(
    const bf16_t* __restrict__ A, const bf16_t* __restrict__ Bt,
    const float* __restrict__ bias, const void* __restrict__ res,
    void* __restrict__ Cv, int K, int lda, int ldb, int ldc)
{
    extern __shared__ ushort lds[];   // 3 x (A:16384 | B:8192) ushorts = 147456 B
    const int tid = threadIdx.x;
    const int l31 = tid & 31, khalf = (tid >> 5) & 1;
    const int w = tid >> 6;
    const int wr = w >> 1, wc = w & 1;      // 4M x 2N

    // XCD-aware swizzle (T1); grids here always have nwg % 8 == 0.
    int gx = gridDim.x;
    int nwg = gx * gridDim.y;
    int id = blockIdx.y * gx + blockIdx.x;
    if ((nwg & 7) == 0) {
        int cpx = nwg >> 3;
        id = (id & 7) * cpx + (id >> 3);
    }
    const int m0 = (id % gx) * 256, n0 = (id / gx) * 128;

    // staging map: pass p -> row p*64 + (tid>>3), phys chunk tid&7; source
    // column pre-swizzled so LDS phys chunk c holds logical chunk c^(row&7).
    const int srow = tid >> 3;
    const int sg = (((tid & 7) ^ (srow & 7)) << 3);
    const ushort* gA = (const ushort*)A + (size_t)(m0 + srow) * lda + sg;
    const ushort* gB = (const ushort*)Bt + (size_t)(n0 + srow) * ldb + sg;
    const int dOff = tid * 8;

    f32x16 acc[2][2] = {};
    const int arow = wr * 64, brow = wc * 64;
    const int nk = K >> 6;                  // always >= 3 here (12 or 48)

    ushort* b0 = lds;                       // tile kt   (consume)
    ushort* b1 = lds + 24576;               // tile kt+1 (in flight, issued kt-1)
    ushort* b2 = lds + 49152;               // tile kt+2 (issue this tile)

    // 6 glds per thread per tile: 4 A passes (64 rows each) + 2 B passes.
    auto STAGE = [&](int t, ushort* buf) {
        const size_t ko = (size_t)t << 6;
#pragma unroll
        for (int p = 0; p < 4; ++p)
            glds16(gA + ko + (size_t)(p * 64) * lda, buf + p * 4096 + dOff);
#pragma unroll
        for (int p = 0; p < 2; ++p)
            glds16(gB + ko + (size_t)(p * 64) * ldb, buf + 16384 + p * 4096 + dOff);
    };

    // prologue: tiles 0 and 1 in flight; wait only tile 0 (oldest 6).
    STAGE(0, b0);
    STAGE(1, b1);
    asm volatile("s_waitcnt vmcnt(6)" ::: "memory");
    __builtin_amdgcn_s_barrier();

    for (int kt = 0; kt < nk; ++kt) {
        if (kt + 2 < nk) STAGE(kt + 2, b2);   // issue early; lands >1 tile later
        __builtin_amdgcn_s_setprio(1);
#pragma unroll
        for (int kk = 0; kk < 4; ++kk) {
            const int pc = (((kk * 2 + khalf) ^ (l31 & 7)) << 3);
            bf16x8 a0 = *(const bf16x8*)&b0[(arow + l31) * 64 + pc];
            bf16x8 a1 = *(const bf16x8*)&b0[(arow + 32 + l31) * 64 + pc];
            bf16x8 f0 = *(const bf16x8*)&b0[16384 + (brow + l31) * 64 + pc];
            bf16x8 f1 = *(const bf16x8*)&b0[16384 + (brow + 32 + l31) * 64 + pc];
            // SWAPPED operands: D lane=m, regs=n
            acc[0][0] = __builtin_amdgcn_mfma_f32_32x32x16_bf16(f0, a0, acc[0][0], 0, 0, 0);
            acc[0][1] = __builtin_amdgcn_mfma_f32_32x32x16_bf16(f1, a0, acc[0][1], 0, 0, 0);
            acc[1][0] = __builtin_amdgcn_mfma_f32_32x32x16_bf16(f0, a1, acc[1][0], 0, 0, 0);
            acc[1][1] = __builtin_amdgcn_mfma_f32_32x32x16_bf16(f1, a1, acc[1][1], 0, 0, 0);
        }
        __builtin_amdgcn_s_setprio(0);
        if (kt + 1 < nk) {
            // wait ONLY tile kt+1's 6 loads (oldest); kt+2's 6 stay in flight.
            if (kt + 2 < nk) asm volatile("s_waitcnt vmcnt(6)" ::: "memory");
            else             asm volatile("s_waitcnt vmcnt(0)" ::: "memory");
            __builtin_amdgcn_s_barrier();
        }
        ushort* t0 = b0; b0 = b1; b1 = b2; b2 = t0;   // rotate buffers
    }

    // Epilogue: m = m0 + wr*64 + mi*32 + l31; reg g*4+r -> n = n0 + wc*64 + ni*32 + 8g + 4*khalf + r
#pragma unroll
    for (int mi = 0; mi < 2; ++mi) {
        int m = m0 + arow + mi * 32 + l31;
#pragma unroll
        for (int ni = 0; ni < 2; ++ni) {
#pragma unroll
            for (int g = 0; g < 4; ++g) {
                int nb = n0 + brow + ni * 32 + 8 * g + 4 * khalf;
                float4 bv4 = *(const float4*)&bias[nb];
                float v[4];
#pragma unroll
                for (int r = 0; r < 4; ++r) v[r] = acc[mi][ni][g * 4 + r] + ((const float*)&bv4)[r];
                if constexpr (EPI == 1) {
#pragma unroll
                    for (int r = 0; r < 4; ++r) v[r] = gelu_f(v[r]);
                }
                ushort4 st;
                st.x = f2bu(v[0]); st.y = f2bu(v[1]); st.z = f2bu(v[2]); st.w = f2bu(v[3]);
                if constexpr (EPI == 6) {
                    int seg = n0 / 768;      // block-uniform (768 % 128 == 0)
                    int nloc = (n0 % 768) + brow + ni * 32 + 8 * g + 4 * khalf;
                    if (seg < 2) {
                        bf16_t* Cseg = (bf16_t*)Cv + (size_t)seg * 6291456;
                        *(ushort4*)&((ushort*)Cseg)[(size_t)m * 768 + nloc] = st;
                    } else {
                        // V segment -> Vt[h][d][s'] via faithful flat reshape
                        ushort* vt = (ushort*)res;
                        int fb = (m & 511) * 768 + nloc;
                        int h = (m >> 9) * 12 + (fb >> 15);
                        int d = fb & 63;
                        int s = (fb >> 6) & 511;
                        ushort* vh = vt + (size_t)h * 32768 + s;
                        vh[(size_t)(d + 0) * 512] = st.x;
                        vh[(size_t)(d + 1) * 512] = st.y;
                        vh[(size_t)(d + 2) * 512] = st.z;
                        vh[(size_t)(d + 3) * 512] = st.w;
                    }
                } else {
                    *(ushort4*)&((ushort*)Cv)[(size_t)m * ldc + nb] = st;
                }
            }
        }
    }
}

// ---------------------------------------------------------------------------
// NT GEMM, BK=64, swapped-operand mfma_f32_32x32x16_bf16 (round-10 kernel,
// retained for O-proj and FFN2 where N=768; 2-3 blocks/CU hide its drains).
// ---------------------------------------------------------------------------
template <int EPI, int NTILE>
__global__ __launch_bounds__(256) void gemm128(
    const bf16_t* __restrict__ A, const bf16_t* __restrict__ Bt,
    const float* __restrict__ bias, const void* __restrict__ res,
    void* __restrict__ Cv, int K, int lda, int ldb, int ldc)
{
    __shared__ ushort lA[128 * 64];
    __shared__ ushort lB[NTILE * 64];
    constexpr int NI = NTILE / 64;           // 32x32 n-subtiles per wave
    const int tid = threadIdx.x;
    const int l = tid & 63, w = tid >> 6;
    const int l31 = l & 31, khalf = l >> 5;  // frag row / k-half
    const int m0 = blockIdx.x * 128, n0 = blockIdx.y * NTILE;

    const int srow = tid >> 3;
    const int sg = (((tid & 7) ^ (srow & 7)) << 3);
    const ushort* gA = (const ushort*)A + (size_t)(m0 + srow) * lda + sg;
    const ushort* gB = (const ushort*)Bt + (size_t)(n0 + srow) * ldb + sg;
    ushort* dA = lA + tid * 8;
    ushort* dB = lB + tid * 8;

    f32x16 acc[2][NI] = {};
    const int arow = (w & 1) * 64;
    const int brow = (w >> 1) * (NTILE / 2);

    for (int k0 = 0; k0 < K; k0 += 64) {
        __syncthreads();
        glds16(gA + k0,                      dA);
        glds16(gA + k0 + (size_t)32 * lda,   dA + 2048);
        glds16(gA + k0 + (size_t)64 * lda,   dA + 4096);
        glds16(gA + k0 + (size_t)96 * lda,   dA + 6144);
        glds16(gB + k0,                      dB);
        glds16(gB + k0 + (size_t)32 * ldb,   dB + 2048);
        if constexpr (NTILE == 128) {
            glds16(gB + k0 + (size_t)64 * ldb, dB + 4096);
            glds16(gB + k0 + (size_t)96 * ldb, dB + 6144);
        }
        __syncthreads();
#pragma unroll
        for (int kk = 0; kk < 4; ++kk) {
            const int pc = (((kk * 2 + khalf) ^ (l31 & 7)) << 3);
            bf16x8 bfr[NI];
#pragma unroll
            for (int ni = 0; ni < NI; ++ni)
                bfr[ni] = *(const bf16x8*)&lB[(brow + ni * 32 + l31) * 64 + pc];
#pragma unroll
            for (int mi = 0; mi < 2; ++mi) {
                bf16x8 afr = *(const bf16x8*)&lA[(arow + mi * 32 + l31) * 64 + pc];
#pragma unroll
                for (int ni = 0; ni < NI; ++ni)   // SWAPPED: D lane=m, regs=n
                    acc[mi][ni] = __builtin_amdgcn_mfma_f32_32x32x16_bf16(bfr[ni], afr, acc[mi][ni], 0, 0, 0);
            }
        }
    }

    // Epilogue: m = arow + mi*32 + l31; reg g*4+r -> n = ni*32 + 8g + 4*khalf + r
#pragma unroll
    for (int mi = 0; mi < 2; ++mi) {
        int m = m0 + arow + mi * 32 + l31;
#pragma unroll
        for (int ni = 0; ni < NI; ++ni) {
#pragma unroll
            for (int g = 0; g < 4; ++g) {
                int nb = n0 + brow + ni * 32 + 8 * g + 4 * khalf;  // 4 consecutive n
                float4 bv4 = *(const float4*)&bias[nb];
                float v[4];
#pragma unroll
                for (int r = 0; r < 4; ++r) v[r] = acc[mi][ni][g * 4 + r] + ((const float*)&bv4)[r];
                if constexpr (EPI == 1) {
#pragma unroll
                    for (int r = 0; r < 4; ++r) v[r] = gelu_f(v[r]);
                } else if constexpr (EPI == 2) {
                    float4 r4 = *(const float4*)&((const float*)res)[(size_t)m * ldc + nb];
#pragma unroll
                    for (int r = 0; r < 4; ++r) v[r] += ((const float*)&r4)[r];
                } else if constexpr (EPI == 5) {
                    ushort4 rb = *(const ushort4*)&((const ushort*)res)[(size_t)m * ldc + nb];
#pragma unroll
                    for (int r = 0; r < 4; ++r) v[r] += b2f(*(const bf16_t*)&((const ushort*)&rb)[r]);
                }
                if constexpr (EPI == 5) {
                    *(float4*)&((float*)Cv)[(size_t)m * ldc + nb] = make_float4(v[0], v[1], v[2], v[3]);
                } else {
                    ushort4 st;
                    st.x = f2bu(v[0]); st.y = f2bu(v[1]); st.z = f2bu(v[2]); st.w = f2bu(v[3]);
                    if constexpr (EPI == 6) {
                        int seg = n0 / 768;      // block-uniform (768 % NTILE == 0)
                        int nloc = (n0 % 768) + brow + ni * 32 + 8 * g + 4 * khalf;
                        if (seg < 2) {
                            bf16_t* Cseg = (bf16_t*)Cv + (size_t)seg * 6291456;
                            *(ushort4*)&((ushort*)Cseg)[(size_t)m * 768 + nloc] = st;
                        } else {
                            ushort* vt = (ushort*)res;
                            int fb = (m & 511) * 768 + nloc;
                            int h = (m >> 9) * 12 + (fb >> 15);
                            int d = fb & 63;
                            int s = (fb >> 6) & 511;
                            ushort* vh = vt + (size_t)h * 32768 + s;
                            vh[(size_t)(d + 0) * 512] = st.x;
                            vh[(size_t)(d + 1) * 512] = st.y;
                            vh[(size_t)(d + 2) * 512] = st.z;
                            vh[(size_t)(d + 3) * 512] = st.w;
                        }
                    } else {
                        *(ushort4*)&((ushort*)Cv)[(size_t)m * ldc + nb] = st;
                    }
                }
            }
        }
    }
}

// ---------------------------------------------------------------------------
// Flash attention, Q-tile 128, swapped-operand 16x16x32 MFMA (round-9 verified).
// ---------------------------------------------------------------------------
__global__ __launch_bounds__(256) void flash_kernel(
    const bf16_t* __restrict__ Q, const bf16_t* __restrict__ Kx,
    const bf16_t* __restrict__ Vt, const int* __restrict__ mask,
    bf16_t* __restrict__ Z)
{
    __shared__ ushort lK[64 * 64];
    __shared__ ushort lV[64 * 64];
    __shared__ ushort lP[128 * 72];

    const int h = blockIdx.y;
    const int q0 = blockIdx.x * 128;
    const ushort* Qh = (const ushort*)Q + (size_t)h * 32768;
    const ushort* Kh = (const ushort*)Kx + (size_t)h * 32768;
    const ushort* Vh = (const ushort*)Vt + (size_t)h * 32768;   // [64][512]
    const int* mk = mask + (h / 12) * 512;
    ushort* Zh = (ushort*)Z + (size_t)h * 32768;

    const int tid = threadIdx.x;
    const int l = tid & 63, w = tid >> 6;
    const int l16 = l & 15, quad = l >> 4;

    bf16x8 qfr[2][2];   // [mi][kk]
#pragma unroll
    for (int mi = 0; mi < 2; ++mi)
#pragma unroll
        for (int kk = 0; kk < 2; ++kk)
            qfr[mi][kk] = *(const bf16x8*)(Qh + (size_t)(q0 + w * 32 + mi * 16 + l16) * 64 + kk * 32 + quad * 8);

    const int c8p = tid & 7;
    const int kr0 = tid >> 3;
    float m_i[2] = {-1e30f, -1e30f}, l_i[2] = {0.f, 0.f};
    f32x4 o4[2][4] = {};

    for (int kt = 0; kt < 8; ++kt) {
#pragma unroll
        for (int p = 0; p < 2; ++p) {
            int row = kr0 + p * 32;
            int c8l = c8p ^ (row & 7);
            glds16(Kh + (size_t)(kt * 64 + row) * 64 + c8l * 8, lK + (p * 256 + tid) * 8);
            glds16(Vh + (size_t)row * 512 + kt * 64 + c8l * 8, lV + (p * 256 + tid) * 8);
        }
        __syncthreads();

        f32x4 s4[2][4] = {};
#pragma unroll
        for (int kk = 0; kk < 2; ++kk) {
#pragma unroll
            for (int nt = 0; nt < 4; ++nt) {
                bf16x8 kfr = *(const bf16x8*)&lK[(nt * 16 + l16) * 64 + (((kk * 4 + quad) ^ (l16 & 7)) << 3)];
#pragma unroll
                for (int mi = 0; mi < 2; ++mi)
                    s4[mi][nt] = __builtin_amdgcn_mfma_f32_16x16x32_bf16(kfr, qfr[mi][kk], s4[mi][nt], 0, 0, 0);
            }
        }

        int4 m4[4];
#pragma unroll
        for (int nt = 0; nt < 4; ++nt) m4[nt] = *(const int4*)&mk[kt * 64 + nt * 16 + quad * 4];

#pragma unroll
        for (int mi = 0; mi < 2; ++mi) {
            float pv[4][4];
            float rm = -1e30f;
#pragma unroll
            for (int nt = 0; nt < 4; ++nt)
#pragma unroll
                for (int r = 0; r < 4; ++r) {
                    float v = (((const int*)&m4[nt])[r] == 0) ? -1e30f : s4[mi][nt][r] * 0.125f;
                    pv[nt][r] = v;
                    rm = fmaxf(rm, v);
                }
            rm = fmaxf(rm, __shfl_xor(rm, 16));
            rm = fmaxf(rm, __shfl_xor(rm, 32));
            float mn = fmaxf(m_i[mi], rm);
            float al = __expf(m_i[mi] - mn);
            float rs = 0.f;
#pragma unroll
            for (int nt = 0; nt < 4; ++nt)
#pragma unroll
                for (int r = 0; r < 4; ++r) {
                    float e = __expf(pv[nt][r] - mn);
                    pv[nt][r] = e;
                    rs += e;
                }
            rs += __shfl_xor(rs, 16);
            rs += __shfl_xor(rs, 32);
            l_i[mi] = l_i[mi] * al + rs;
            m_i[mi] = mn;
#pragma unroll
            for (int dt = 0; dt < 4; ++dt)
#pragma unroll
                for (int r = 0; r < 4; ++r) o4[mi][dt][r] *= al;

#pragma unroll
            for (int nt = 0; nt < 4; ++nt) {
                ushort4 st;
                st.x = f2bu(pv[nt][0]); st.y = f2bu(pv[nt][1]);
                st.z = f2bu(pv[nt][2]); st.w = f2bu(pv[nt][3]);
                *(ushort4*)&lP[(w * 32 + mi * 16 + l16) * 72 + nt * 16 + quad * 4] = st;
            }
        }
        __syncthreads();

#pragma unroll
        for (int kk = 0; kk < 2; ++kk) {
#pragma unroll
            for (int dt = 0; dt < 4; ++dt) {
                bf16x8 bvfr = *(const bf16x8*)&lV[(dt * 16 + l16) * 64 + (((kk * 4 + quad) ^ (l16 & 7)) << 3)];
#pragma unroll
                for (int mi = 0; mi < 2; ++mi) {
                    bf16x8 pafr = *(const bf16x8*)&lP[(w * 32 + mi * 16 + l16) * 72 + kk * 32 + quad * 8];
                    o4[mi][dt] = __builtin_amdgcn_mfma_f32_16x16x32_bf16(bvfr, pafr, o4[mi][dt], 0, 0, 0);
                }
            }
        }
        __syncthreads();
    }

#pragma unroll
    for (int mi = 0; mi < 2; ++mi) {
        float inv = 1.f / l_i[mi];
#pragma unroll
        for (int dt = 0; dt < 4; ++dt) {
            ushort4 st;
            st.x = f2bu(o4[mi][dt][0] * inv); st.y = f2bu(o4[mi][dt][1] * inv);
            st.z = f2bu(o4[mi][dt][2] * inv); st.w = f2bu(o4[mi][dt][3] * inv);
            *(ushort4*)&Zh[(size_t)(q0 + w * 32 + mi * 16 + l16) * 64 + dt * 16 + quad * 4] = st;
        }
    }
}

// ---------------------------------------------------------------------------
// LayerNorm over H=768, one block per row, fp32 stats. In-place safe.
// ---------------------------------------------------------------------------
__device__ __forceinline__ float to_f(float v)  { return v; }
__device__ __forceinline__ float to_f(bf16_t v) { return b2f(v); }
__device__ __forceinline__ void from_f(float& d, float v)  { d = v; }
__device__ __forceinline__ void from_f(bf16_t& d, float v) { d = f2b(v); }

template <typename TI, typename TO>
__global__ __launch_bounds__(256) void layernorm_kernel(
    const TI* __restrict__ X, const float* __restrict__ w,
    const float* __restrict__ b, TO* __restrict__ out)
{
    const TI* x = X + (size_t)blockIdx.x * 768;
    TO* o = out + (size_t)blockIdx.x * 768;
    int t = threadIdx.x;
    float v[3];
    float s = 0.f, sq = 0.f;
#pragma unroll
    for (int i = 0; i < 3; ++i) {
        v[i] = to_f(x[t + i * 256]);
        s += v[i]; sq += v[i] * v[i];
    }
#pragma unroll
    for (int off = 32; off; off >>= 1) { s += __shfl_xor(s, off); sq += __shfl_xor(sq, off); }
    __shared__ float s1[4], s2[4];
    int wave = t >> 6, lane = t & 63;
    if (lane == 0) { s1[wave] = s; s2[wave] = sq; }
    __syncthreads();
    s  = s1[0] + s1[1] + s1[2] + s1[3];
    sq = s2[0] + s2[1] + s2[2] + s2[3];
    float mu  = s * (1.f / 768.f);
    float var = sq * (1.f / 768.f) - mu * mu;
    float rs  = rsqrtf(var + 1e-5f);
#pragma unroll
    for (int i = 0; i < 3; ++i)
        from_f(o[t + i * 256], (v[i] - mu) * rs * w[t + i * 256] + b[t + i * 256]);
}

// ---------------------------------------------------------------------------
extern "C" void kernel_launch(void* const* d_in, const int* in_sizes, int n_in,
                              void* d_out, int out_size, void* d_ws, size_t ws_size,
                              hipStream_t stream)
{
    const float* X    = (const float*)d_in[0];
    const int*   mask = (const int*)  d_in[1];
    const float* WQ   = (const float*)d_in[2];
    const float* bQ   = (const float*)d_in[3];
    const float* WK   = (const float*)d_in[4];
    const float* bK   = (const float*)d_in[5];
    const float* WV   = (const float*)d_in[6];
    const float* bV   = (const float*)d_in[7];
    const float* WO   = (const float*)d_in[8];
    const float* bO   = (const float*)d_in[9];
    const float* ln1w = (const float*)d_in[10];
    const float* ln1b = (const float*)d_in[11];
    const float* W1   = (const float*)d_in[12];
    const float* b1   = (const float*)d_in[13];
    const float* W2   = (const float*)d_in[14];
    const float* b2   = (const float*)d_in[15];
    const float* ln2w = (const float*)d_in[16];
    const float* ln2b = (const float*)d_in[17];
    float* out = (float*)d_out;

    // ---- workspace (bf16 elems; total 38,539,776 = 77.1 MB) ----
    bf16_t* ws   = (bf16_t*)d_ws;
    bf16_t* Wqkv = ws;                        // [2304][768] (WQt|WKt|WVt)
    bf16_t* WOt  = Wqkv + 1769472;            // [768][768]
    bf16_t* W1t  = WOt + 589824;              // [3072][768]
    bf16_t* W2t  = W1t + 2359296;             // [768][3072]
    float*  bcat = (float*)(W2t + 2359296);   // fp32[2304] (= 4608 bf16)
    bf16_t* Qb   = W2t + 2359296 + 4608;      // packed [8192][768]; Q,K consecutive (EPI 6)
    bf16_t* Kb   = Qb + 6291456;
    bf16_t* Vb   = Kb + 6291456;              // (layout hold)
    bf16_t* Xb   = Vb + 6291456;              // bf16 X (dead after QKV; Y1 alias)
    bf16_t* Vt   = Xb + 6291456;              // per-head V^T [192][64][512], from QKV epilogue
    // aliases (dead-before-write):
    bf16_t* Zb = Qb;   // flash writes Z in-place over Q
    bf16_t* Y1 = Xb;   // O-proj out (Xb dead after QKV gemm)
    bf16_t* X1 = Qb;   // LN1 out (Qb/Z dead after O-proj)
    bf16_t* Hb = Kb;   // FFN mid [8192][3072] = Kb+Vb+Xb+Vt exactly

    // allow 144 KiB dynamic LDS for gemm_v3 (host-side attribute, capture-safe)
    (void)hipFuncSetAttribute(reinterpret_cast<const void*>(&gemm_v3<6>),
                              hipFuncAttributeMaxDynamicSharedMemorySize, 147456);
    (void)hipFuncSetAttribute(reinterpret_cast<const void*>(&gemm_v3<1>),
                              hipFuncAttributeMaxDynamicSharedMemorySize, 147456);

    // ---- 1. prep ----
    prep_kernel<<<4801, 256, 0, stream>>>(WQ, WK, WV, WO, W1, W2, bQ, bK, bV, X,
                                          Wqkv, WOt, W1t, W2t, bcat, Xb);

    // ---- 2. fused QKV projection -> packed Q/K + transposed Vt (v3) ----
    gemm_v3<6><<<dim3(32, 18), 512, 147456, stream>>>(Xb, Wqkv, bcat, Vt, Qb,
                                                      768, 768, 768, 768);

    // ---- 3. flash attention (Q-tile 128), Z in-place over Q ----
    flash_kernel<<<dim3(4, 192), 256, 0, stream>>>(Qb, Kb, Vt, mask, Zb);

    // ---- 4. O-projection + fp32 residual -> Y1, LN1 -> X1 ----
    gemm128<2, 64><<<dim3(64, 12), 256, 0, stream>>>(Zb, WOt, bO, X, Y1,
                                                     768, 768, 768, 768);
    layernorm_kernel<bf16_t, bf16_t><<<8192, 256, 0, stream>>>(Y1, ln1w, ln1b, X1);

    // ---- 5. FFN ----
    gemm_v3<1><<<dim3(32, 24), 512, 147456, stream>>>(X1, W1t, b1, nullptr, Hb,
                                                      768, 768, 768, 3072);
    gemm128<5, 64><<<dim3(64, 12), 256, 0, stream>>>(Hb, W2t, b2, X1, out,
                                                     3072, 3072, 3072, 768);
    layernorm_kernel<float, float><<<8192, 256, 0, stream>>>(out, ln2w, ln2b, out);
}

// Round 3
// 417.156 us; speedup vs baseline: 1.0504x; 1.0504x over previous
//
#include <hip/hip_runtime.h>
#include <hip/hip_bf16.h>

// Encoder layer. fp32 in/out, bf16 MFMA compute, fp32 accum.
// B=16 S=512 H=768 A=12 DH=64 F=3072.
// Round 13: gemm_v4 — BM=256 BN=256 BK=32, 8 waves (2Mx4N, WAVE TILE 128x64,
// acc[4][2] f32x16). Rationale: 64x64 wave tile = 1.0 b128-read/MFMA ->
// LDS-read-BW caps MfmaUtil ~50%; 128x64 = 0.75 -> ~90%+ headroom.
//   - A|B packed per K-tile buffer [256 rows][64 ushorts]: chunks 0-3 = A k,
//     chunks 4-7 = B k. Keeps the PROVEN 8-chunk XOR swizzle (phys = clog ^
//     (row&7)) at BK=32. glds16 dest stays linear (rule: wave base+lane*16);
//     source pre-swizzled per thread (A-or-B chosen by clog at setup).
//   - 4 buffers x 32 KiB = 128 KiB, prefetch depth 3: issue(kt+3) ~3 tiles
//     (~3000 cy) before wait -> covers 900 cy HBM miss. vmcnt(8) steady
//     (leaves kt+2,kt+3 in flight), 1 s_barrier per K-tile.
//   - NO XCD swizzle: r12's swizzle gave each XCD ALL of A (8x12.6 MB = the
//     measured 114 MB fetch). Default round-robin keeps per-XCD A-slices
//     L2-resident (31 MB fetch).
// Fragment/epilogue math identical to proven gemm128 (mi extended 2->4):
// phys chunk = clog ^ (row&7); D swapped: lane=m, reg g*4+r -> n=8g+4khalf+r.
// FFN2 (N=768, K=3072: 96 blocks would starve CUs) stays on gemm128.

using bf16_t = __hip_bfloat16;
typedef __bf16 bf16x8 __attribute__((ext_vector_type(8)));
typedef float f32x4 __attribute__((ext_vector_type(4)));
typedef float f32x16 __attribute__((ext_vector_type(16)));

__device__ __forceinline__ float b2f(bf16_t v) { return __bfloat162float(v); }
__device__ __forceinline__ bf16_t f2b(float v) { return __float2bfloat16(v); }
__device__ __forceinline__ ushort f2bu(float v) { bf16_t b = f2b(v); return *(ushort*)&b; }

// async global->LDS 16B copy (dest = wave base + lane*16 by construction)
__device__ __forceinline__ void glds16(const ushort* g, ushort* l) {
    __builtin_amdgcn_global_load_lds(
        (const __attribute__((address_space(1))) unsigned int*)g,
        (__attribute__((address_space(3))) unsigned int*)l, 16, 0, 0);
}

// tanh-form GELU (overflow-safe), |err vs exact| ~1e-3 << 0.102 threshold
__device__ __forceinline__ float gelu_f(float x) {
    float x2 = x * x;
    float y2 = 1.5957691216057308f * x * fmaf(0.044715f, x2, 1.0f);
    float e = __expf(y2);
    float t = 1.f - 2.f / (e + 1.f);
    return 0.5f * x * (1.f + t);
}

// ---------------------------------------------------------------------------
// Prep mega-kernel: 6 weight transposes + bias concat + X cast. One launch.
// ---------------------------------------------------------------------------
__device__ __forceinline__ void tr_tile(const float* __restrict__ in,
                                        bf16_t* __restrict__ out,
                                        int R, int C, int tx, int ty,
                                        float (*t)[65], int tid)
{
    int r0 = ty * 64, c0 = tx * 64;
    int tr = tid >> 6, tc = tid & 63;
#pragma unroll 4
    for (int i = 0; i < 16; ++i) {
        int r = i * 4 + tr;
        t[r][tc] = in[(size_t)(r0 + r) * C + c0 + tc];
    }
    __syncthreads();
#pragma unroll 4
    for (int i = 0; i < 16; ++i) {
        int r = i * 4 + tr;
        out[(size_t)(c0 + r) * R + r0 + tc] = f2b(t[tc][r]);
    }
}

__global__ __launch_bounds__(256) void prep_kernel(
    const float* __restrict__ WQ, const float* __restrict__ WK,
    const float* __restrict__ WV, const float* __restrict__ WO,
    const float* __restrict__ W1, const float* __restrict__ W2,
    const float* __restrict__ bQ, const float* __restrict__ bK,
    const float* __restrict__ bV, const float* __restrict__ X,
    bf16_t* __restrict__ Wqkv, bf16_t* __restrict__ WOt,
    bf16_t* __restrict__ W1t, bf16_t* __restrict__ W2t,
    float* __restrict__ bcat, bf16_t* __restrict__ Xb)
{
    __shared__ float t[64][65];
    const int blk = blockIdx.x, tid = threadIdx.x;
    if (blk < 576) {
        int m = blk / 144, tt = blk % 144;
        const float* in = (m == 0) ? WQ : (m == 1) ? WK : (m == 2) ? WV : WO;
        bf16_t* out = (m == 0) ? Wqkv : (m == 1) ? Wqkv + 589824
                    : (m == 2) ? Wqkv + 1179648 : WOt;
        tr_tile(in, out, 768, 768, tt % 12, tt / 12, t, tid);
    } else if (blk < 1152) {
        int tt = blk - 576;
        tr_tile(W1, W1t, 768, 3072, tt % 48, tt / 48, t, tid);
    } else if (blk < 1728) {
        int tt = blk - 1152;
        tr_tile(W2, W2t, 3072, 768, tt % 12, tt / 12, t, tid);
    } else if (blk == 1728) {
        for (int i = tid; i < 2304; i += 256)
            bcat[i] = (i < 768) ? bQ[i] : (i < 1536) ? bK[i - 768] : bV[i - 1536];
    } else {
        size_t i = ((size_t)(blk - 1729) * 256 + tid) * 8;
        float4 a = *(const float4*)(X + i);
        float4 b = *(const float4*)(X + i + 4);
#pragma unroll
        for (int j = 0; j < 4; ++j) {
            Xb[i + j]     = f2b(((const float*)&a)[j]);
            Xb[i + 4 + j] = f2b(((const float*)&b)[j]);
        }
    }
}

// ---------------------------------------------------------------------------
// gemm_v4: NT GEMM, 256x256 tile, BK=32, 512 thr = 8 waves (2Mx4N),
// wave tile 128x64. 4-deep LDS ring (128 KiB), prefetch distance 3,
// counted vmcnt(8) + single s_barrier per K-tile. See header comment.
// EPI: 1 bias+GELU->bf16 | 2 bias+res(fp32,ld=ldc)->bf16 | 6 segmented QKV.
// Requires nk = K/32 >= 3 (K = 768 here -> 24).
// ---------------------------------------------------------------------------
template <int EPI>
__global__ __launch_bounds__(512, 1) void gemm_v4(
    const bf16_t* __restrict__ A, const bf16_t* __restrict__ Bt,
    const float* __restrict__ bias, const void* __restrict__ res,
    void* __restrict__ Cv, int K, int lda, int ldb, int ldc)
{
    extern __shared__ ushort lds[];   // 4 buffers x [256][64] ushorts = 128 KiB
    const int tid = threadIdx.x;
    const int l31 = tid & 31, khalf = (tid >> 5) & 1;
    const int w = tid >> 6;
    const int wr = w >> 2, wc = w & 3;      // 2M x 4N, wave tile 128x64
    const int m0 = blockIdx.x * 256, n0 = blockIdx.y * 256;

    // Staging: pass p covers buffer rows p*64 + (tid>>3), phys chunk tid&7.
    // logical chunk clog = phys ^ (row&7); clog 0-3 = A k-chunk, 4-7 = B.
    // (row&7) == ((tid>>3)&7) for every pass since p*64 % 8 == 0.
    const ushort* src[4];
#pragma unroll
    for (int p = 0; p < 4; ++p) {
        int row = p * 64 + (tid >> 3);
        int clog = (tid & 7) ^ (row & 7);
        src[p] = (clog < 4)
            ? (const ushort*)A  + (size_t)(m0 + row) * lda + clog * 8
            : (const ushort*)Bt + (size_t)(n0 + row) * ldb + (clog - 4) * 8;
    }
    const int dOff = tid * 8;

    auto STAGE = [&](int t, ushort* buf) {
        const int ko = t << 5;              // 32 k-elems per tile
#pragma unroll
        for (int p = 0; p < 4; ++p)
            glds16(src[p] + ko, buf + p * 4096 + dOff);
    };

    f32x16 acc[4][2] = {};
    const int arow = wr * 128, brow = wc * 64;
    const int nk = K >> 5;                  // >= 3 required

    // prologue: 3 tiles in flight; wait tile 0 (oldest 4 of 12) -> vmcnt(8)
    STAGE(0, lds);
    STAGE(1, lds + 16384);
    STAGE(2, lds + 32768);
    asm volatile("s_waitcnt vmcnt(8)" ::: "memory");
    __builtin_amdgcn_s_barrier();

    for (int kt = 0; kt < nk; ++kt) {
        if (kt + 3 < nk) STAGE(kt + 3, lds + ((kt + 3) & 3) * 16384);
        const ushort* bt = lds + (kt & 3) * 16384;
        __builtin_amdgcn_s_setprio(1);
#pragma unroll
        for (int kk = 0; kk < 2; ++kk) {
            const int ca = (((kk * 2 + khalf)     ^ (l31 & 7)) << 3);
            const int cb = (((4 + kk * 2 + khalf) ^ (l31 & 7)) << 3);
            bf16x8 afr[4], bfr[2];
#pragma unroll
            for (int mi = 0; mi < 4; ++mi)
                afr[mi] = *(const bf16x8*)&bt[(arow + mi * 32 + l31) * 64 + ca];
#pragma unroll
            for (int ni = 0; ni < 2; ++ni)
                bfr[ni] = *(const bf16x8*)&bt[(brow + ni * 32 + l31) * 64 + cb];
#pragma unroll
            for (int mi = 0; mi < 4; ++mi)
#pragma unroll
                for (int ni = 0; ni < 2; ++ni)   // SWAPPED: D lane=m, regs=n
                    acc[mi][ni] = __builtin_amdgcn_mfma_f32_32x32x16_bf16(bfr[ni], afr[mi], acc[mi][ni], 0, 0, 0);
        }
        __builtin_amdgcn_s_setprio(0);
        // wait ONLY the oldest in-flight tile (kt+1); deeper ones stay out.
        if (kt + 3 < nk)      asm volatile("s_waitcnt vmcnt(8)" ::: "memory");
        else if (kt + 2 < nk) asm volatile("s_waitcnt vmcnt(4)" ::: "memory");
        else if (kt + 1 < nk) asm volatile("s_waitcnt vmcnt(0)" ::: "memory");
        if (kt + 1 < nk) __builtin_amdgcn_s_barrier();
    }

    // Epilogue: m = m0 + wr*128 + mi*32 + l31; reg g*4+r -> n = n0 + wc*64 + ni*32 + 8g + 4khalf + r
#pragma unroll
    for (int mi = 0; mi < 4; ++mi) {
        int m = m0 + arow + mi * 32 + l31;
#pragma unroll
        for (int ni = 0; ni < 2; ++ni) {
#pragma unroll
            for (int g = 0; g < 4; ++g) {
                int nb = n0 + brow + ni * 32 + 8 * g + 4 * khalf;
                float4 bv4 = *(const float4*)&bias[nb];
                float v[4];
#pragma unroll
                for (int r = 0; r < 4; ++r) v[r] = acc[mi][ni][g * 4 + r] + ((const float*)&bv4)[r];
                if constexpr (EPI == 1) {
#pragma unroll
                    for (int r = 0; r < 4; ++r) v[r] = gelu_f(v[r]);
                } else if constexpr (EPI == 2) {
                    float4 r4 = *(const float4*)&((const float*)res)[(size_t)m * ldc + nb];
#pragma unroll
                    for (int r = 0; r < 4; ++r) v[r] += ((const float*)&r4)[r];
                }
                ushort4 st;
                st.x = f2bu(v[0]); st.y = f2bu(v[1]); st.z = f2bu(v[2]); st.w = f2bu(v[3]);
                if constexpr (EPI == 6) {
                    int seg = n0 / 768;      // block-uniform (n0 % 768 in {0,256,512}; tiles never straddle)
                    int nloc = (n0 % 768) + brow + ni * 32 + 8 * g + 4 * khalf;
                    if (seg < 2) {
                        bf16_t* Cseg = (bf16_t*)Cv + (size_t)seg * 6291456;
                        *(ushort4*)&((ushort*)Cseg)[(size_t)m * 768 + nloc] = st;
                    } else {
                        // V segment -> Vt[h][d][s'] via faithful flat reshape
                        ushort* vt = (ushort*)res;
                        int fb = (m & 511) * 768 + nloc;
                        int h = (m >> 9) * 12 + (fb >> 15);
                        int d = fb & 63;
                        int s = (fb >> 6) & 511;
                        ushort* vh = vt + (size_t)h * 32768 + s;
                        vh[(size_t)(d + 0) * 512] = st.x;
                        vh[(size_t)(d + 1) * 512] = st.y;
                        vh[(size_t)(d + 2) * 512] = st.z;
                        vh[(size_t)(d + 3) * 512] = st.w;
                    }
                } else {
                    *(ushort4*)&((ushort*)Cv)[(size_t)m * ldc + nb] = st;
                }
            }
        }
    }
}

// ---------------------------------------------------------------------------
// NT GEMM, BK=64, swapped-operand mfma_f32_32x32x16_bf16 (round-10 kernel,
// retained for FFN2: N=768 x K=3072 -> 768 blocks keep all CUs busy, and
// 2-3 blocks/CU hide the per-tile drains).
// ---------------------------------------------------------------------------
template <int EPI, int NTILE>
__global__ __launch_bounds__(256) void gemm128(
    const bf16_t* __restrict__ A, const bf16_t* __restrict__ Bt,
    const float* __restrict__ bias, const void* __restrict__ res,
    void* __restrict__ Cv, int K, int lda, int ldb, int ldc)
{
    __shared__ ushort lA[128 * 64];
    __shared__ ushort lB[NTILE * 64];
    constexpr int NI = NTILE / 64;           // 32x32 n-subtiles per wave
    const int tid = threadIdx.x;
    const int l = tid & 63, w = tid >> 6;
    const int l31 = l & 31, khalf = l >> 5;  // frag row / k-half
    const int m0 = blockIdx.x * 128, n0 = blockIdx.y * NTILE;

    const int srow = tid >> 3;
    const int sg = (((tid & 7) ^ (srow & 7)) << 3);
    const ushort* gA = (const ushort*)A + (size_t)(m0 + srow) * lda + sg;
    const ushort* gB = (const ushort*)Bt + (size_t)(n0 + srow) * ldb + sg;
    ushort* dA = lA + tid * 8;
    ushort* dB = lB + tid * 8;

    f32x16 acc[2][NI] = {};
    const int arow = (w & 1) * 64;
    const int brow = (w >> 1) * (NTILE / 2);

    for (int k0 = 0; k0 < K; k0 += 64) {
        __syncthreads();
        glds16(gA + k0,                      dA);
        glds16(gA + k0 + (size_t)32 * lda,   dA + 2048);
        glds16(gA + k0 + (size_t)64 * lda,   dA + 4096);
        glds16(gA + k0 + (size_t)96 * lda,   dA + 6144);
        glds16(gB + k0,                      dB);
        glds16(gB + k0 + (size_t)32 * ldb,   dB + 2048);
        if constexpr (NTILE == 128) {
            glds16(gB + k0 + (size_t)64 * ldb, dB + 4096);
            glds16(gB + k0 + (size_t)96 * ldb, dB + 6144);
        }
        __syncthreads();
#pragma unroll
        for (int kk = 0; kk < 4; ++kk) {
            const int pc = (((kk * 2 + khalf) ^ (l31 & 7)) << 3);
            bf16x8 bfr[NI];
#pragma unroll
            for (int ni = 0; ni < NI; ++ni)
                bfr[ni] = *(const bf16x8*)&lB[(brow + ni * 32 + l31) * 64 + pc];
#pragma unroll
            for (int mi = 0; mi < 2; ++mi) {
                bf16x8 afr = *(const bf16x8*)&lA[(arow + mi * 32 + l31) * 64 + pc];
#pragma unroll
                for (int ni = 0; ni < NI; ++ni)   // SWAPPED: D lane=m, regs=n
                    acc[mi][ni] = __builtin_amdgcn_mfma_f32_32x32x16_bf16(bfr[ni], afr, acc[mi][ni], 0, 0, 0);
            }
        }
    }

    // Epilogue: m = arow + mi*32 + l31; reg g*4+r -> n = ni*32 + 8g + 4*khalf + r
#pragma unroll
    for (int mi = 0; mi < 2; ++mi) {
        int m = m0 + arow + mi * 32 + l31;
#pragma unroll
        for (int ni = 0; ni < NI; ++ni) {
#pragma unroll
            for (int g = 0; g < 4; ++g) {
                int nb = n0 + brow + ni * 32 + 8 * g + 4 * khalf;  // 4 consecutive n
                float4 bv4 = *(const float4*)&bias[nb];
                float v[4];
#pragma unroll
                for (int r = 0; r < 4; ++r) v[r] = acc[mi][ni][g * 4 + r] + ((const float*)&bv4)[r];
                if constexpr (EPI == 1) {
#pragma unroll
                    for (int r = 0; r < 4; ++r) v[r] = gelu_f(v[r]);
                } else if constexpr (EPI == 2) {
                    float4 r4 = *(const float4*)&((const float*)res)[(size_t)m * ldc + nb];
#pragma unroll
                    for (int r = 0; r < 4; ++r) v[r] += ((const float*)&r4)[r];
                } else if constexpr (EPI == 5) {
                    ushort4 rb = *(const ushort4*)&((const ushort*)res)[(size_t)m * ldc + nb];
#pragma unroll
                    for (int r = 0; r < 4; ++r) v[r] += b2f(*(const bf16_t*)&((const ushort*)&rb)[r]);
                }
                if constexpr (EPI == 5) {
                    *(float4*)&((float*)Cv)[(size_t)m * ldc + nb] = make_float4(v[0], v[1], v[2], v[3]);
                } else {
                    ushort4 st;
                    st.x = f2bu(v[0]); st.y = f2bu(v[1]); st.z = f2bu(v[2]); st.w = f2bu(v[3]);
                    *(ushort4*)&((ushort*)Cv)[(size_t)m * ldc + nb] = st;
                }
            }
        }
    }
}

// ---------------------------------------------------------------------------
// Flash attention, Q-tile 128, swapped-operand 16x16x32 MFMA (round-9 verified).
// ---------------------------------------------------------------------------
__global__ __launch_bounds__(256) void flash_kernel(
    const bf16_t* __restrict__ Q, const bf16_t* __restrict__ Kx,
    const bf16_t* __restrict__ Vt, const int* __restrict__ mask,
    bf16_t* __restrict__ Z)
{
    __shared__ ushort lK[64 * 64];
    __shared__ ushort lV[64 * 64];
    __shared__ ushort lP[128 * 72];

    const int h = blockIdx.y;
    const int q0 = blockIdx.x * 128;
    const ushort* Qh = (const ushort*)Q + (size_t)h * 32768;
    const ushort* Kh = (const ushort*)Kx + (size_t)h * 32768;
    const ushort* Vh = (const ushort*)Vt + (size_t)h * 32768;   // [64][512]
    const int* mk = mask + (h / 12) * 512;
    ushort* Zh = (ushort*)Z + (size_t)h * 32768;

    const int tid = threadIdx.x;
    const int l = tid & 63, w = tid >> 6;
    const int l16 = l & 15, quad = l >> 4;

    bf16x8 qfr[2][2];   // [mi][kk]
#pragma unroll
    for (int mi = 0; mi < 2; ++mi)
#pragma unroll
        for (int kk = 0; kk < 2; ++kk)
            qfr[mi][kk] = *(const bf16x8*)(Qh + (size_t)(q0 + w * 32 + mi * 16 + l16) * 64 + kk * 32 + quad * 8);

    const int c8p = tid & 7;
    const int kr0 = tid >> 3;
    float m_i[2] = {-1e30f, -1e30f}, l_i[2] = {0.f, 0.f};
    f32x4 o4[2][4] = {};

    for (int kt = 0; kt < 8; ++kt) {
#pragma unroll
        for (int p = 0; p < 2; ++p) {
            int row = kr0 + p * 32;
            int c8l = c8p ^ (row & 7);
            glds16(Kh + (size_t)(kt * 64 + row) * 64 + c8l * 8, lK + (p * 256 + tid) * 8);
            glds16(Vh + (size_t)row * 512 + kt * 64 + c8l * 8, lV + (p * 256 + tid) * 8);
        }
        __syncthreads();

        f32x4 s4[2][4] = {};
#pragma unroll
        for (int kk = 0; kk < 2; ++kk) {
#pragma unroll
            for (int nt = 0; nt < 4; ++nt) {
                bf16x8 kfr = *(const bf16x8*)&lK[(nt * 16 + l16) * 64 + (((kk * 4 + quad) ^ (l16 & 7)) << 3)];
#pragma unroll
                for (int mi = 0; mi < 2; ++mi)
                    s4[mi][nt] = __builtin_amdgcn_mfma_f32_16x16x32_bf16(kfr, qfr[mi][kk], s4[mi][nt], 0, 0, 0);
            }
        }

        int4 m4[4];
#pragma unroll
        for (int nt = 0; nt < 4; ++nt) m4[nt] = *(const int4*)&mk[kt * 64 + nt * 16 + quad * 4];

#pragma unroll
        for (int mi = 0; mi < 2; ++mi) {
            float pv[4][4];
            float rm = -1e30f;
#pragma unroll
            for (int nt = 0; nt < 4; ++nt)
#pragma unroll
                for (int r = 0; r < 4; ++r) {
                    float v = (((const int*)&m4[nt])[r] == 0) ? -1e30f : s4[mi][nt][r] * 0.125f;
                    pv[nt][r] = v;
                    rm = fmaxf(rm, v);
                }
            rm = fmaxf(rm, __shfl_xor(rm, 16));
            rm = fmaxf(rm, __shfl_xor(rm, 32));
            float mn = fmaxf(m_i[mi], rm);
            float al = __expf(m_i[mi] - mn);
            float rs = 0.f;
#pragma unroll
            for (int nt = 0; nt < 4; ++nt)
#pragma unroll
                for (int r = 0; r < 4; ++r) {
                    float e = __expf(pv[nt][r] - mn);
                    pv[nt][r] = e;
                    rs += e;
                }
            rs += __shfl_xor(rs, 16);
            rs += __shfl_xor(rs, 32);
            l_i[mi] = l_i[mi] * al + rs;
            m_i[mi] = mn;
#pragma unroll
            for (int dt = 0; dt < 4; ++dt)
#pragma unroll
                for (int r = 0; r < 4; ++r) o4[mi][dt][r] *= al;

#pragma unroll
            for (int nt = 0; nt < 4; ++nt) {
                ushort4 st;
                st.x = f2bu(pv[nt][0]); st.y = f2bu(pv[nt][1]);
                st.z = f2bu(pv[nt][2]); st.w = f2bu(pv[nt][3]);
                *(ushort4*)&lP[(w * 32 + mi * 16 + l16) * 72 + nt * 16 + quad * 4] = st;
            }
        }
        __syncthreads();

#pragma unroll
        for (int kk = 0; kk < 2; ++kk) {
#pragma unroll
            for (int dt = 0; dt < 4; ++dt) {
                bf16x8 bvfr = *(const bf16x8*)&lV[(dt * 16 + l16) * 64 + (((kk * 4 + quad) ^ (l16 & 7)) << 3)];
#pragma unroll
                for (int mi = 0; mi < 2; ++mi) {
                    bf16x8 pafr = *(const bf16x8*)&lP[(w * 32 + mi * 16 + l16) * 72 + kk * 32 + quad * 8];
                    o4[mi][dt] = __builtin_amdgcn_mfma_f32_16x16x32_bf16(bvfr, pafr, o4[mi][dt], 0, 0, 0);
                }
            }
        }
        __syncthreads();
    }

#pragma unroll
    for (int mi = 0; mi < 2; ++mi) {
        float inv = 1.f / l_i[mi];
#pragma unroll
        for (int dt = 0; dt < 4; ++dt) {
            ushort4 st;
            st.x = f2bu(o4[mi][dt][0] * inv); st.y = f2bu(o4[mi][dt][1] * inv);
            st.z = f2bu(o4[mi][dt][2] * inv); st.w = f2bu(o4[mi][dt][3] * inv);
            *(ushort4*)&Zh[(size_t)(q0 + w * 32 + mi * 16 + l16) * 64 + dt * 16 + quad * 4] = st;
        }
    }
}

// ---------------------------------------------------------------------------
// LayerNorm over H=768, one block per row, fp32 stats. In-place safe.
// ---------------------------------------------------------------------------
__device__ __forceinline__ float to_f(float v)  { return v; }
__device__ __forceinline__ float to_f(bf16_t v) { return b2f(v); }
__device__ __forceinline__ void from_f(float& d, float v)  { d = v; }
__device__ __forceinline__ void from_f(bf16_t& d, float v) { d = f2b(v); }

template <typename TI, typename TO>
__global__ __launch_bounds__(256) void layernorm_kernel(
    const TI* __restrict__ X, const float* __restrict__ w,
    const float* __restrict__ b, TO* __restrict__ out)
{
    const TI* x = X + (size_t)blockIdx.x * 768;
    TO* o = out + (size_t)blockIdx.x * 768;
    int t = threadIdx.x;
    float v[3];
    float s = 0.f, sq = 0.f;
#pragma unroll
    for (int i = 0; i < 3; ++i) {
        v[i] = to_f(x[t + i * 256]);
        s += v[i]; sq += v[i] * v[i];
    }
#pragma unroll
    for (int off = 32; off; off >>= 1) { s += __shfl_xor(s, off); sq += __shfl_xor(sq, off); }
    __shared__ float s1[4], s2[4];
    int wave = t >> 6, lane = t & 63;
    if (lane == 0) { s1[wave] = s; s2[wave] = sq; }
    __syncthreads();
    s  = s1[0] + s1[1] + s1[2] + s1[3];
    sq = s2[0] + s2[1] + s2[2] + s2[3];
    float mu  = s * (1.f / 768.f);
    float var = sq * (1.f / 768.f) - mu * mu;
    float rs  = rsqrtf(var + 1e-5f);
#pragma unroll
    for (int i = 0; i < 3; ++i)
        from_f(o[t + i * 256], (v[i] - mu) * rs * w[t + i * 256] + b[t + i * 256]);
}

// ---------------------------------------------------------------------------
extern "C" void kernel_launch(void* const* d_in, const int* in_sizes, int n_in,
                              void* d_out, int out_size, void* d_ws, size_t ws_size,
                              hipStream_t stream)
{
    const float* X    = (const float*)d_in[0];
    const int*   mask = (const int*)  d_in[1];
    const float* WQ   = (const float*)d_in[2];
    const float* bQ   = (const float*)d_in[3];
    const float* WK   = (const float*)d_in[4];
    const float* bK   = (const float*)d_in[5];
    const float* WV   = (const float*)d_in[6];
    const float* bV   = (const float*)d_in[7];
    const float* WO   = (const float*)d_in[8];
    const float* bO   = (const float*)d_in[9];
    const float* ln1w = (const float*)d_in[10];
    const float* ln1b = (const float*)d_in[11];
    const float* W1   = (const float*)d_in[12];
    const float* b1   = (const float*)d_in[13];
    const float* W2   = (const float*)d_in[14];
    const float* b2   = (const float*)d_in[15];
    const float* ln2w = (const float*)d_in[16];
    const float* ln2b = (const float*)d_in[17];
    float* out = (float*)d_out;

    // ---- workspace (bf16 elems; total 38,539,776 = 77.1 MB) ----
    bf16_t* ws   = (bf16_t*)d_ws;
    bf16_t* Wqkv = ws;                        // [2304][768] (WQt|WKt|WVt)
    bf16_t* WOt  = Wqkv + 1769472;            // [768][768]
    bf16_t* W1t  = WOt + 589824;              // [3072][768]
    bf16_t* W2t  = W1t + 2359296;             // [768][3072]
    float*  bcat = (float*)(W2t + 2359296);   // fp32[2304] (= 4608 bf16)
    bf16_t* Qb   = W2t + 2359296 + 4608;      // packed [8192][768]; Q,K consecutive (EPI 6)
    bf16_t* Kb   = Qb + 6291456;
    bf16_t* Vb   = Kb + 6291456;              // (layout hold)
    bf16_t* Xb   = Vb + 6291456;              // bf16 X (dead after QKV; Y1 alias)
    bf16_t* Vt   = Xb + 6291456;              // per-head V^T [192][64][512], from QKV epilogue
    // aliases (dead-before-write):
    bf16_t* Zb = Qb;   // flash writes Z in-place over Q
    bf16_t* Y1 = Xb;   // O-proj out (Xb dead after QKV gemm)
    bf16_t* X1 = Qb;   // LN1 out (Qb/Z dead after O-proj)
    bf16_t* Hb = Kb;   // FFN mid [8192][3072] = Kb+Vb+Xb+Vt exactly

    // allow 128 KiB dynamic LDS for gemm_v4 (host-side attribute, capture-safe)
    (void)hipFuncSetAttribute(reinterpret_cast<const void*>(&gemm_v4<6>),
                              hipFuncAttributeMaxDynamicSharedMemorySize, 131072);
    (void)hipFuncSetAttribute(reinterpret_cast<const void*>(&gemm_v4<2>),
                              hipFuncAttributeMaxDynamicSharedMemorySize, 131072);
    (void)hipFuncSetAttribute(reinterpret_cast<const void*>(&gemm_v4<1>),
                              hipFuncAttributeMaxDynamicSharedMemorySize, 131072);

    // ---- 1. prep ----
    prep_kernel<<<4801, 256, 0, stream>>>(WQ, WK, WV, WO, W1, W2, bQ, bK, bV, X,
                                          Wqkv, WOt, W1t, W2t, bcat, Xb);

    // ---- 2. fused QKV projection -> packed Q/K + transposed Vt ----
    gemm_v4<6><<<dim3(32, 9), 512, 131072, stream>>>(Xb, Wqkv, bcat, Vt, Qb,
                                                     768, 768, 768, 768);

    // ---- 3. flash attention (Q-tile 128), Z in-place over Q ----
    flash_kernel<<<dim3(4, 192), 256, 0, stream>>>(Qb, Kb, Vt, mask, Zb);

    // ---- 4. O-projection + fp32 residual -> Y1, LN1 -> X1 ----
    gemm_v4<2><<<dim3(32, 3), 512, 131072, stream>>>(Zb, WOt, bO, X, Y1,
                                                     768, 768, 768, 768);
    layernorm_kernel<bf16_t, bf16_t><<<8192, 256, 0, stream>>>(Y1, ln1w, ln1b, X1);

    // ---- 5. FFN ----
    gemm_v4<1><<<dim3(32, 12), 512, 131072, stream>>>(X1, W1t, b1, nullptr, Hb,
                                                      768, 768, 768, 3072);
    gemm128<5, 64><<<dim3(64, 12), 256, 0, stream>>>(Hb, W2t, b2, X1, out,
                                                     3072, 3072, 3072, 768);
    layernorm_kernel<float, float><<<8192, 256, 0, stream>>>(out, ln2w, ln2b, out);
}

// Round 4
// 371.782 us; speedup vs baseline: 1.1787x; 1.1220x over previous
//
#include <hip/hip_runtime.h>
#include <hip/hip_bf16.h>

// Encoder layer. fp32 in/out, bf16 MFMA compute, fp32 accum.
// B=16 S=512 H=768 A=12 DH=64 F=3072.
// Round 14: reset to round-10 baseline (gemm128 for QKV/Oproj/FFN2) +
// catalog-exact 2-phase 256^2 kernel (gemm_2ph) on FFN1 ONLY, as the
// validated A/B base for the 8-phase escalation.
//   gemm_2ph = T3 "minimum 2-phase" box: STAGE(t+1,buf^1) -> compute(buf)
//   -> vmcnt(0) -> s_barrier. 8 waves (2Mx4N, wave 128x64, acc[4][2]),
//   BK=64, 2 x 64 KiB LDS. Stage latency hides under the 32-MFMA compute
//   cluster (r13's ring had no such overlap structure and hit 478 TF;
//   catalog 2ph = 655-682 TF refcheck'd).
// Fragment/swizzle math (proven gemm128): phys chunk = (kk*2+khalf) ^
// (row&7); D swapped: lane=m, reg g*4+r -> n=8g+4*khalf+r.

using bf16_t = __hip_bfloat16;
typedef __bf16 bf16x8 __attribute__((ext_vector_type(8)));
typedef float f32x4 __attribute__((ext_vector_type(4)));
typedef float f32x16 __attribute__((ext_vector_type(16)));

__device__ __forceinline__ float b2f(bf16_t v) { return __bfloat162float(v); }
__device__ __forceinline__ bf16_t f2b(float v) { return __float2bfloat16(v); }
__device__ __forceinline__ ushort f2bu(float v) { bf16_t b = f2b(v); return *(ushort*)&b; }

// async global->LDS 16B copy (dest = wave base + lane*16 by construction)
__device__ __forceinline__ void glds16(const ushort* g, ushort* l) {
    __builtin_amdgcn_global_load_lds(
        (const __attribute__((address_space(1))) unsigned int*)g,
        (__attribute__((address_space(3))) unsigned int*)l, 16, 0, 0);
}

// tanh-form GELU (overflow-safe), |err vs exact| ~1e-3 << 0.102 threshold
__device__ __forceinline__ float gelu_f(float x) {
    float x2 = x * x;
    float y2 = 1.5957691216057308f * x * fmaf(0.044715f, x2, 1.0f);
    float e = __expf(y2);
    float t = 1.f - 2.f / (e + 1.f);
    return 0.5f * x * (1.f + t);
}

// ---------------------------------------------------------------------------
// Prep mega-kernel: 6 weight transposes + bias concat + X cast. One launch.
// ---------------------------------------------------------------------------
__device__ __forceinline__ void tr_tile(const float* __restrict__ in,
                                        bf16_t* __restrict__ out,
                                        int R, int C, int tx, int ty,
                                        float (*t)[65], int tid)
{
    int r0 = ty * 64, c0 = tx * 64;
    int tr = tid >> 6, tc = tid & 63;
#pragma unroll 4
    for (int i = 0; i < 16; ++i) {
        int r = i * 4 + tr;
        t[r][tc] = in[(size_t)(r0 + r) * C + c0 + tc];
    }
    __syncthreads();
#pragma unroll 4
    for (int i = 0; i < 16; ++i) {
        int r = i * 4 + tr;
        out[(size_t)(c0 + r) * R + r0 + tc] = f2b(t[tc][r]);
    }
}

__global__ __launch_bounds__(256) void prep_kernel(
    const float* __restrict__ WQ, const float* __restrict__ WK,
    const float* __restrict__ WV, const float* __restrict__ WO,
    const float* __restrict__ W1, const float* __restrict__ W2,
    const float* __restrict__ bQ, const float* __restrict__ bK,
    const float* __restrict__ bV, const float* __restrict__ X,
    bf16_t* __restrict__ Wqkv, bf16_t* __restrict__ WOt,
    bf16_t* __restrict__ W1t, bf16_t* __restrict__ W2t,
    float* __restrict__ bcat, bf16_t* __restrict__ Xb)
{
    __shared__ float t[64][65];
    const int blk = blockIdx.x, tid = threadIdx.x;
    if (blk < 576) {
        int m = blk / 144, tt = blk % 144;
        const float* in = (m == 0) ? WQ : (m == 1) ? WK : (m == 2) ? WV : WO;
        bf16_t* out = (m == 0) ? Wqkv : (m == 1) ? Wqkv + 589824
                    : (m == 2) ? Wqkv + 1179648 : WOt;
        tr_tile(in, out, 768, 768, tt % 12, tt / 12, t, tid);
    } else if (blk < 1152) {
        int tt = blk - 576;
        tr_tile(W1, W1t, 768, 3072, tt % 48, tt / 48, t, tid);
    } else if (blk < 1728) {
        int tt = blk - 1152;
        tr_tile(W2, W2t, 3072, 768, tt % 12, tt / 12, t, tid);
    } else if (blk == 1728) {
        for (int i = tid; i < 2304; i += 256)
            bcat[i] = (i < 768) ? bQ[i] : (i < 1536) ? bK[i - 768] : bV[i - 1536];
    } else {
        size_t i = ((size_t)(blk - 1729) * 256 + tid) * 8;
        float4 a = *(const float4*)(X + i);
        float4 b = *(const float4*)(X + i + 4);
#pragma unroll
        for (int j = 0; j < 4; ++j) {
            Xb[i + j]     = f2b(((const float*)&a)[j]);
            Xb[i + 4 + j] = f2b(((const float*)&b)[j]);
        }
    }
}

// ---------------------------------------------------------------------------
// gemm_2ph: NT GEMM, 256x256 tile, BK=64, 512 thr = 8 waves (2Mx4N),
// wave tile 128x64, acc[4][2]. Catalog-exact 2-phase double buffer:
//   prologue: STAGE(0,b0); vmcnt(0); barrier
//   loop t<nk-1: STAGE(t+1,b^1); setprio(1) COMPUTE(b) setprio(0);
//                vmcnt(0); barrier; b^=1
//   tail: COMPUTE(b)
// One barrier per K-tile; stage latency hides under the 32-MFMA cluster.
// EPI: 1 bias+GELU->bf16.
// ---------------------------------------------------------------------------
template <int EPI>
__global__ __launch_bounds__(512, 1) void gemm_2ph(
    const bf16_t* __restrict__ A, const bf16_t* __restrict__ Bt,
    const float* __restrict__ bias, const void* __restrict__ res,
    void* __restrict__ Cv, int K, int lda, int ldb, int ldc)
{
    extern __shared__ ushort lds[];   // 2 buf x (A 16384 | B 16384) ushorts = 128 KiB
    const int tid = threadIdx.x;
    const int l31 = tid & 31, khalf = (tid >> 5) & 1;
    const int w = tid >> 6;
    const int wr = w >> 2, wc = w & 3;      // 2M x 4N
    const int m0 = blockIdx.x * 256, n0 = blockIdx.y * 256;

    // staging map: pass p -> row p*64 + (tid>>3), phys chunk tid&7; source
    // column pre-swizzled so LDS phys chunk c holds logical chunk c^(row&7).
    const int srow = tid >> 3;
    const int sg = (((tid & 7) ^ (srow & 7)) << 3);
    const ushort* gA = (const ushort*)A + (size_t)(m0 + srow) * lda + sg;
    const ushort* gB = (const ushort*)Bt + (size_t)(n0 + srow) * ldb + sg;
    const int dOff = tid * 8;

    f32x16 acc[4][2] = {};
    const int arow = wr * 128, brow = wc * 64;
    const int nk = K >> 6;

    STAGE_DEF:;
    auto STAGE = [&](int t, int cur) {
        ushort* buf = lds + cur * 32768;
        const size_t ko = (size_t)t << 6;
#pragma unroll
        for (int p = 0; p < 4; ++p)
            glds16(gA + ko + (size_t)(p * 64) * lda, buf + p * 4096 + dOff);
#pragma unroll
        for (int p = 0; p < 4; ++p)
            glds16(gB + ko + (size_t)(p * 64) * ldb, buf + 16384 + p * 4096 + dOff);
    };

    auto COMPUTE = [&](int cur) {
        const ushort* buf = lds + cur * 32768;
#pragma unroll
        for (int kk = 0; kk < 4; ++kk) {
            const int pc = (((kk * 2 + khalf) ^ (l31 & 7)) << 3);
            bf16x8 afr[4], bfr[2];
#pragma unroll
            for (int mi = 0; mi < 4; ++mi)
                afr[mi] = *(const bf16x8*)&buf[(arow + mi * 32 + l31) * 64 + pc];
#pragma unroll
            for (int ni = 0; ni < 2; ++ni)
                bfr[ni] = *(const bf16x8*)&buf[16384 + (brow + ni * 32 + l31) * 64 + pc];
#pragma unroll
            for (int mi = 0; mi < 4; ++mi)
#pragma unroll
                for (int ni = 0; ni < 2; ++ni)   // SWAPPED: D lane=m, regs=n
                    acc[mi][ni] = __builtin_amdgcn_mfma_f32_32x32x16_bf16(bfr[ni], afr[mi], acc[mi][ni], 0, 0, 0);
        }
    };

    // prologue
    STAGE(0, 0);
    asm volatile("s_waitcnt vmcnt(0)" ::: "memory");
    __builtin_amdgcn_s_barrier();

    int cur = 0;
    for (int t = 0; t < nk - 1; ++t) {
        STAGE(t + 1, cur ^ 1);              // issue next-tile loads FIRST
        __builtin_amdgcn_s_setprio(1);
        COMPUTE(cur);                       // 24 ds_read + 32 MFMA hide them
        __builtin_amdgcn_s_setprio(0);
        asm volatile("s_waitcnt vmcnt(0)" ::: "memory");
        __builtin_amdgcn_s_barrier();
        cur ^= 1;
    }
    COMPUTE(cur);                           // tail: no prefetch

    // Epilogue: m = m0 + wr*128 + mi*32 + l31; reg g*4+r -> n = n0 + wc*64 + ni*32 + 8g + 4khalf + r
#pragma unroll
    for (int mi = 0; mi < 4; ++mi) {
        int m = m0 + arow + mi * 32 + l31;
#pragma unroll
        for (int ni = 0; ni < 2; ++ni) {
#pragma unroll
            for (int g = 0; g < 4; ++g) {
                int nb = n0 + brow + ni * 32 + 8 * g + 4 * khalf;
                float4 bv4 = *(const float4*)&bias[nb];
                float v[4];
#pragma unroll
                for (int r = 0; r < 4; ++r) v[r] = acc[mi][ni][g * 4 + r] + ((const float*)&bv4)[r];
                if constexpr (EPI == 1) {
#pragma unroll
                    for (int r = 0; r < 4; ++r) v[r] = gelu_f(v[r]);
                }
                ushort4 st;
                st.x = f2bu(v[0]); st.y = f2bu(v[1]); st.z = f2bu(v[2]); st.w = f2bu(v[3]);
                *(ushort4*)&((ushort*)Cv)[(size_t)m * ldc + nb] = st;
            }
        }
    }
}

// ---------------------------------------------------------------------------
// NT GEMM, BK=64, swapped-operand mfma_f32_32x32x16_bf16 (round-10 proven
// kernel: QKV (EPI 6), O-proj (EPI 2), FFN2 (EPI 5)).
// Tile 128 x NTILE x 64, 256 thr = 4 waves.
// ---------------------------------------------------------------------------
template <int EPI, int NTILE>
__global__ __launch_bounds__(256) void gemm128(
    const bf16_t* __restrict__ A, const bf16_t* __restrict__ Bt,
    const float* __restrict__ bias, const void* __restrict__ res,
    void* __restrict__ Cv, int K, int lda, int ldb, int ldc)
{
    __shared__ ushort lA[128 * 64];
    __shared__ ushort lB[NTILE * 64];
    constexpr int NI = NTILE / 64;           // 32x32 n-subtiles per wave
    const int tid = threadIdx.x;
    const int l = tid & 63, w = tid >> 6;
    const int l31 = l & 31, khalf = l >> 5;  // frag row / k-half
    const int m0 = blockIdx.x * 128, n0 = blockIdx.y * NTILE;

    const int srow = tid >> 3;
    const int sg = (((tid & 7) ^ (srow & 7)) << 3);
    const ushort* gA = (const ushort*)A + (size_t)(m0 + srow) * lda + sg;
    const ushort* gB = (const ushort*)Bt + (size_t)(n0 + srow) * ldb + sg;
    ushort* dA = lA + tid * 8;
    ushort* dB = lB + tid * 8;

    f32x16 acc[2][NI] = {};
    const int arow = (w & 1) * 64;
    const int brow = (w >> 1) * (NTILE / 2);

    for (int k0 = 0; k0 < K; k0 += 64) {
        __syncthreads();
        glds16(gA + k0,                      dA);
        glds16(gA + k0 + (size_t)32 * lda,   dA + 2048);
        glds16(gA + k0 + (size_t)64 * lda,   dA + 4096);
        glds16(gA + k0 + (size_t)96 * lda,   dA + 6144);
        glds16(gB + k0,                      dB);
        glds16(gB + k0 + (size_t)32 * ldb,   dB + 2048);
        if constexpr (NTILE == 128) {
            glds16(gB + k0 + (size_t)64 * ldb, dB + 4096);
            glds16(gB + k0 + (size_t)96 * ldb, dB + 6144);
        }
        __syncthreads();
#pragma unroll
        for (int kk = 0; kk < 4; ++kk) {
            const int pc = (((kk * 2 + khalf) ^ (l31 & 7)) << 3);
            bf16x8 bfr[NI];
#pragma unroll
            for (int ni = 0; ni < NI; ++ni)
                bfr[ni] = *(const bf16x8*)&lB[(brow + ni * 32 + l31) * 64 + pc];
#pragma unroll
            for (int mi = 0; mi < 2; ++mi) {
                bf16x8 afr = *(const bf16x8*)&lA[(arow + mi * 32 + l31) * 64 + pc];
#pragma unroll
                for (int ni = 0; ni < NI; ++ni)   // SWAPPED: D lane=m, regs=n
                    acc[mi][ni] = __builtin_amdgcn_mfma_f32_32x32x16_bf16(bfr[ni], afr, acc[mi][ni], 0, 0, 0);
            }
        }
    }

    // Epilogue: m = arow + mi*32 + l31; reg g*4+r -> n = ni*32 + 8g + 4*khalf + r
#pragma unroll
    for (int mi = 0; mi < 2; ++mi) {
        int m = m0 + arow + mi * 32 + l31;
#pragma unroll
        for (int ni = 0; ni < NI; ++ni) {
#pragma unroll
            for (int g = 0; g < 4; ++g) {
                int nb = n0 + brow + ni * 32 + 8 * g + 4 * khalf;  // 4 consecutive n
                float4 bv4 = *(const float4*)&bias[nb];
                float v[4];
#pragma unroll
                for (int r = 0; r < 4; ++r) v[r] = acc[mi][ni][g * 4 + r] + ((const float*)&bv4)[r];
                if constexpr (EPI == 1) {
#pragma unroll
                    for (int r = 0; r < 4; ++r) v[r] = gelu_f(v[r]);
                } else if constexpr (EPI == 2) {
                    float4 r4 = *(const float4*)&((const float*)res)[(size_t)m * ldc + nb];
#pragma unroll
                    for (int r = 0; r < 4; ++r) v[r] += ((const float*)&r4)[r];
                } else if constexpr (EPI == 5) {
                    ushort4 rb = *(const ushort4*)&((const ushort*)res)[(size_t)m * ldc + nb];
#pragma unroll
                    for (int r = 0; r < 4; ++r) v[r] += b2f(*(const bf16_t*)&((const ushort*)&rb)[r]);
                }
                if constexpr (EPI == 5) {
                    *(float4*)&((float*)Cv)[(size_t)m * ldc + nb] = make_float4(v[0], v[1], v[2], v[3]);
                } else {
                    ushort4 st;
                    st.x = f2bu(v[0]); st.y = f2bu(v[1]); st.z = f2bu(v[2]); st.w = f2bu(v[3]);
                    if constexpr (EPI == 6) {
                        int seg = n0 / 768;      // block-uniform (768 % NTILE == 0)
                        int nloc = (n0 % 768) + brow + ni * 32 + 8 * g + 4 * khalf;
                        if (seg < 2) {
                            bf16_t* Cseg = (bf16_t*)Cv + (size_t)seg * 6291456;
                            *(ushort4*)&((ushort*)Cseg)[(size_t)m * 768 + nloc] = st;
                        } else {
                            // V segment -> Vt[h][d][s'] via faithful flat reshape:
                            // fb = (m&511)*768 + nloc; a=fb>>15; s'=(fb>>6)&511; d=fb&63.
                            ushort* vt = (ushort*)res;
                            int fb = (m & 511) * 768 + nloc;
                            int h = (m >> 9) * 12 + (fb >> 15);
                            int d = fb & 63;
                            int s = (fb >> 6) & 511;
                            ushort* vh = vt + (size_t)h * 32768 + s;
                            vh[(size_t)(d + 0) * 512] = st.x;
                            vh[(size_t)(d + 1) * 512] = st.y;
                            vh[(size_t)(d + 2) * 512] = st.z;
                            vh[(size_t)(d + 3) * 512] = st.w;
                        }
                    } else {
                        *(ushort4*)&((ushort*)Cv)[(size_t)m * ldc + nb] = st;
                    }
                }
            }
        }
    }
}

// ---------------------------------------------------------------------------
// Flash attention, Q-tile 128, swapped-operand 16x16x32 MFMA (round-9 verified).
// ---------------------------------------------------------------------------
__global__ __launch_bounds__(256) void flash_kernel(
    const bf16_t* __restrict__ Q, const bf16_t* __restrict__ Kx,
    const bf16_t* __restrict__ Vt, const int* __restrict__ mask,
    bf16_t* __restrict__ Z)
{
    __shared__ ushort lK[64 * 64];
    __shared__ ushort lV[64 * 64];
    __shared__ ushort lP[128 * 72];

    const int h = blockIdx.y;
    const int q0 = blockIdx.x * 128;
    const ushort* Qh = (const ushort*)Q + (size_t)h * 32768;
    const ushort* Kh = (const ushort*)Kx + (size_t)h * 32768;
    const ushort* Vh = (const ushort*)Vt + (size_t)h * 32768;   // [64][512]
    const int* mk = mask + (h / 12) * 512;
    ushort* Zh = (ushort*)Z + (size_t)h * 32768;

    const int tid = threadIdx.x;
    const int l = tid & 63, w = tid >> 6;
    const int l16 = l & 15, quad = l >> 4;

    bf16x8 qfr[2][2];   // [mi][kk]
#pragma unroll
    for (int mi = 0; mi < 2; ++mi)
#pragma unroll
        for (int kk = 0; kk < 2; ++kk)
            qfr[mi][kk] = *(const bf16x8*)(Qh + (size_t)(q0 + w * 32 + mi * 16 + l16) * 64 + kk * 32 + quad * 8);

    const int c8p = tid & 7;
    const int kr0 = tid >> 3;
    float m_i[2] = {-1e30f, -1e30f}, l_i[2] = {0.f, 0.f};
    f32x4 o4[2][4] = {};

    for (int kt = 0; kt < 8; ++kt) {
#pragma unroll
        for (int p = 0; p < 2; ++p) {
            int row = kr0 + p * 32;
            int c8l = c8p ^ (row & 7);
            glds16(Kh + (size_t)(kt * 64 + row) * 64 + c8l * 8, lK + (p * 256 + tid) * 8);
            glds16(Vh + (size_t)row * 512 + kt * 64 + c8l * 8, lV + (p * 256 + tid) * 8);
        }
        __syncthreads();

        f32x4 s4[2][4] = {};
#pragma unroll
        for (int kk = 0; kk < 2; ++kk) {
#pragma unroll
            for (int nt = 0; nt < 4; ++nt) {
                bf16x8 kfr = *(const bf16x8*)&lK[(nt * 16 + l16) * 64 + (((kk * 4 + quad) ^ (l16 & 7)) << 3)];
#pragma unroll
                for (int mi = 0; mi < 2; ++mi)
                    s4[mi][nt] = __builtin_amdgcn_mfma_f32_16x16x32_bf16(kfr, qfr[mi][kk], s4[mi][nt], 0, 0, 0);
            }
        }

        int4 m4[4];
#pragma unroll
        for (int nt = 0; nt < 4; ++nt) m4[nt] = *(const int4*)&mk[kt * 64 + nt * 16 + quad * 4];

#pragma unroll
        for (int mi = 0; mi < 2; ++mi) {
            float pv[4][4];
            float rm = -1e30f;
#pragma unroll
            for (int nt = 0; nt < 4; ++nt)
#pragma unroll
                for (int r = 0; r < 4; ++r) {
                    float v = (((const int*)&m4[nt])[r] == 0) ? -1e30f : s4[mi][nt][r] * 0.125f;
                    pv[nt][r] = v;
                    rm = fmaxf(rm, v);
                }
            rm = fmaxf(rm, __shfl_xor(rm, 16));
            rm = fmaxf(rm, __shfl_xor(rm, 32));
            float mn = fmaxf(m_i[mi], rm);
            float al = __expf(m_i[mi] - mn);
            float rs = 0.f;
#pragma unroll
            for (int nt = 0; nt < 4; ++nt)
#pragma unroll
                for (int r = 0; r < 4; ++r) {
                    float e = __expf(pv[nt][r] - mn);
                    pv[nt][r] = e;
                    rs += e;
                }
            rs += __shfl_xor(rs, 16);
            rs += __shfl_xor(rs, 32);
            l_i[mi] = l_i[mi] * al + rs;
            m_i[mi] = mn;
#pragma unroll
            for (int dt = 0; dt < 4; ++dt)
#pragma unroll
                for (int r = 0; r < 4; ++r) o4[mi][dt][r] *= al;

#pragma unroll
            for (int nt = 0; nt < 4; ++nt) {
                ushort4 st;
                st.x = f2bu(pv[nt][0]); st.y = f2bu(pv[nt][1]);
                st.z = f2bu(pv[nt][2]); st.w = f2bu(pv[nt][3]);
                *(ushort4*)&lP[(w * 32 + mi * 16 + l16) * 72 + nt * 16 + quad * 4] = st;
            }
        }
        __syncthreads();

#pragma unroll
        for (int kk = 0; kk < 2; ++kk) {
#pragma unroll
            for (int dt = 0; dt < 4; ++dt) {
                bf16x8 bvfr = *(const bf16x8*)&lV[(dt * 16 + l16) * 64 + (((kk * 4 + quad) ^ (l16 & 7)) << 3)];
#pragma unroll
                for (int mi = 0; mi < 2; ++mi) {
                    bf16x8 pafr = *(const bf16x8*)&lP[(w * 32 + mi * 16 + l16) * 72 + kk * 32 + quad * 8];
                    o4[mi][dt] = __builtin_amdgcn_mfma_f32_16x16x32_bf16(bvfr, pafr, o4[mi][dt], 0, 0, 0);
                }
            }
        }
        __syncthreads();
    }

#pragma unroll
    for (int mi = 0; mi < 2; ++mi) {
        float inv = 1.f / l_i[mi];
#pragma unroll
        for (int dt = 0; dt < 4; ++dt) {
            ushort4 st;
            st.x = f2bu(o4[mi][dt][0] * inv); st.y = f2bu(o4[mi][dt][1] * inv);
            st.z = f2bu(o4[mi][dt][2] * inv); st.w = f2bu(o4[mi][dt][3] * inv);
            *(ushort4*)&Zh[(size_t)(q0 + w * 32 + mi * 16 + l16) * 64 + dt * 16 + quad * 4] = st;
        }
    }
}

// ---------------------------------------------------------------------------
// LayerNorm over H=768, one block per row, fp32 stats. In-place safe.
// ---------------------------------------------------------------------------
__device__ __forceinline__ float to_f(float v)  { return v; }
__device__ __forceinline__ float to_f(bf16_t v) { return b2f(v); }
__device__ __forceinline__ void from_f(float& d, float v)  { d = v; }
__device__ __forceinline__ void from_f(bf16_t& d, float v) { d = f2b(v); }

template <typename TI, typename TO>
__global__ __launch_bounds__(256) void layernorm_kernel(
    const TI* __restrict__ X, const float* __restrict__ w,
    const float* __restrict__ b, TO* __restrict__ out)
{
    const TI* x = X + (size_t)blockIdx.x * 768;
    TO* o = out + (size_t)blockIdx.x * 768;
    int t = threadIdx.x;
    float v[3];
    float s = 0.f, sq = 0.f;
#pragma unroll
    for (int i = 0; i < 3; ++i) {
        v[i] = to_f(x[t + i * 256]);
        s += v[i]; sq += v[i] * v[i];
    }
#pragma unroll
    for (int off = 32; off; off >>= 1) { s += __shfl_xor(s, off); sq += __shfl_xor(sq, off); }
    __shared__ float s1[4], s2[4];
    int wave = t >> 6, lane = t & 63;
    if (lane == 0) { s1[wave] = s; s2[wave] = sq; }
    __syncthreads();
    s  = s1[0] + s1[1] + s1[2] + s1[3];
    sq = s2[0] + s2[1] + s2[2] + s2[3];
    float mu  = s * (1.f / 768.f);
    float var = sq * (1.f / 768.f) - mu * mu;
    float rs  = rsqrtf(var + 1e-5f);
#pragma unroll
    for (int i = 0; i < 3; ++i)
        from_f(o[t + i * 256], (v[i] - mu) * rs * w[t + i * 256] + b[t + i * 256]);
}

// ---------------------------------------------------------------------------
extern "C" void kernel_launch(void* const* d_in, const int* in_sizes, int n_in,
                              void* d_out, int out_size, void* d_ws, size_t ws_size,
                              hipStream_t stream)
{
    const float* X    = (const float*)d_in[0];
    const int*   mask = (const int*)  d_in[1];
    const float* WQ   = (const float*)d_in[2];
    const float* bQ   = (const float*)d_in[3];
    const float* WK   = (const float*)d_in[4];
    const float* bK   = (const float*)d_in[5];
    const float* WV   = (const float*)d_in[6];
    const float* bV   = (const float*)d_in[7];
    const float* WO   = (const float*)d_in[8];
    const float* bO   = (const float*)d_in[9];
    const float* ln1w = (const float*)d_in[10];
    const float* ln1b = (const float*)d_in[11];
    const float* W1   = (const float*)d_in[12];
    const float* b1   = (const float*)d_in[13];
    const float* W2   = (const float*)d_in[14];
    const float* b2   = (const float*)d_in[15];
    const float* ln2w = (const float*)d_in[16];
    const float* ln2b = (const float*)d_in[17];
    float* out = (float*)d_out;

    // ---- workspace (bf16 elems; total 38,539,776 = 77.1 MB) ----
    bf16_t* ws   = (bf16_t*)d_ws;
    bf16_t* Wqkv = ws;                        // [2304][768] (WQt|WKt|WVt)
    bf16_t* WOt  = Wqkv + 1769472;            // [768][768]
    bf16_t* W1t  = WOt + 589824;              // [3072][768]
    bf16_t* W2t  = W1t + 2359296;             // [768][3072]
    float*  bcat = (float*)(W2t + 2359296);   // fp32[2304] (= 4608 bf16)
    bf16_t* Qb   = W2t + 2359296 + 4608;      // packed [8192][768]; Q,K consecutive (EPI 6)
    bf16_t* Kb   = Qb + 6291456;
    bf16_t* Vb   = Kb + 6291456;              // (layout hold)
    bf16_t* Xb   = Vb + 6291456;              // bf16 X (dead after QKV; Y1 alias)
    bf16_t* Vt   = Xb + 6291456;              // per-head V^T [192][64][512], from QKV epilogue
    // aliases (dead-before-write):
    bf16_t* Zb = Qb;   // flash writes Z in-place over Q
    bf16_t* Y1 = Xb;   // O-proj out (Xb dead after QKV gemm)
    bf16_t* X1 = Qb;   // LN1 out (Qb/Z dead after O-proj)
    bf16_t* Hb = Kb;   // FFN mid [8192][3072] = Kb+Vb+Xb+Vt exactly

    // allow 128 KiB dynamic LDS for gemm_2ph (host-side attribute, capture-safe)
    (void)hipFuncSetAttribute(reinterpret_cast<const void*>(&gemm_2ph<1>),
                              hipFuncAttributeMaxDynamicSharedMemorySize, 131072);

    // ---- 1. prep ----
    prep_kernel<<<4801, 256, 0, stream>>>(WQ, WK, WV, WO, W1, W2, bQ, bK, bV, X,
                                          Wqkv, WOt, W1t, W2t, bcat, Xb);

    // ---- 2. fused QKV projection -> packed Q/K + transposed Vt (r10 path) ----
    gemm128<6, 128><<<dim3(64, 18), 256, 0, stream>>>(Xb, Wqkv, bcat, Vt, Qb,
                                                      768, 768, 768, 768);

    // ---- 3. flash attention (Q-tile 128), Z in-place over Q ----
    flash_kernel<<<dim3(4, 192), 256, 0, stream>>>(Qb, Kb, Vt, mask, Zb);

    // ---- 4. O-projection + fp32 residual -> Y1, LN1 -> X1 (r10 path) ----
    gemm128<2, 64><<<dim3(64, 12), 256, 0, stream>>>(Zb, WOt, bO, X, Y1,
                                                     768, 768, 768, 768);
    layernorm_kernel<bf16_t, bf16_t><<<8192, 256, 0, stream>>>(Y1, ln1w, ln1b, X1);

    // ---- 5. FFN: FFN1 on the 2-phase 256^2 kernel (A/B testbed) ----
    gemm_2ph<1><<<dim3(32, 12), 512, 131072, stream>>>(X1, W1t, b1, nullptr, Hb,
                                                       768, 768, 768, 3072);
    gemm128<5, 64><<<dim3(64, 12), 256, 0, stream>>>(Hb, W2t, b2, X1, out,
                                                     3072, 3072, 3072, 768);
    layernorm_kernel<float, float><<<8192, 256, 0, stream>>>(out, ln2w, ln2b, out);
}